// Round 2
// baseline (3577.334 us; speedup 1.0000x reference)
//
#include <hip/hip_runtime.h>
#include <math.h>

#define NN 1024
#define BB 8
#define NS_ITERS 16
#define EPS_SHIFT 0.1f
#define TS 128
#define BK 16
#define LDP 132
#define MB (1u<<20)

// ---------- block reduction helper (result valid on thread 0) ----------
__device__ __forceinline__ float block_sum(float v) {
    #pragma unroll
    for (int off = 32; off > 0; off >>= 1) v += __shfl_down(v, off, 64);
    __shared__ float red[4];
    int lane = threadIdx.x & 63, wid = threadIdx.x >> 6;
    if (lane == 0) red[wid] = v;
    __syncthreads();
    float t = 0.f;
    if (threadIdx.x == 0) t = red[0] + red[1] + red[2] + red[3];
    return t;
}

// ---------- power iteration pieces: y[row] = sum_j |pu[row][j]| * x[j] ----------
__global__ __launch_bounds__(256) void matvec_abs(const float* __restrict__ pu,
                                                  const float* __restrict__ x,
                                                  float* __restrict__ y,
                                                  int use_ones) {
    int row = blockIdx.x;
    const float4* pr = (const float4*)(pu + (size_t)row * NN);
    float4 p = pr[threadIdx.x];
    float s;
    if (use_ones) {
        s = fabsf(p.x) + fabsf(p.y) + fabsf(p.z) + fabsf(p.w);
    } else {
        float4 xx = ((const float4*)x)[threadIdx.x];
        s = fabsf(p.x) * xx.x + fabsf(p.y) * xx.y + fabsf(p.z) * xx.z + fabsf(p.w) * xx.w;
    }
    s = block_sum(s);
    if (threadIdx.x == 0) y[row] = s;
}

__global__ void norm_vec(const float* __restrict__ y, float* __restrict__ v) {
    float ss = 0.f;
    for (int i = threadIdx.x; i < NN; i += 256) { float t = y[i]; ss += t * t; }
    #pragma unroll
    for (int off = 32; off > 0; off >>= 1) ss += __shfl_down(ss, off, 64);
    __shared__ float red[4];
    __shared__ float s_inv;
    int lane = threadIdx.x & 63, wid = threadIdx.x >> 6;
    if (lane == 0) red[wid] = ss;
    __syncthreads();
    if (threadIdx.x == 0) s_inv = rsqrtf(red[0] + red[1] + red[2] + red[3]);
    __syncthreads();
    float inv = s_inv;
    for (int i = threadIdx.x; i < NN; i += 256) v[i] = y[i] * inv;
}

__global__ void dot_vec(const float* __restrict__ a, const float* __restrict__ b,
                        float* __restrict__ out) {
    float s = 0.f;
    for (int i = threadIdx.x; i < NN; i += 256) s += a[i] * b[i];
    s = block_sum(s);
    if (threadIdx.x == 0) out[0] = s;
}

// ---------- deflation: D = N*(|pu| - v w^T - w v^T + lam v v^T) + eps*I ----------
// also accumulates ||D||_F^2 into sc[0] (sc[5] holds lam)
__global__ __launch_bounds__(256) void deflate_kernel(const float* __restrict__ pu,
                                                      const float* __restrict__ v,
                                                      const float* __restrict__ w,
                                                      float* __restrict__ sc,
                                                      float* __restrict__ D) {
    int idx = blockIdx.x * 256 + threadIdx.x;   // over NN*NN/4
    int row = idx >> 8;
    int c0 = (idx & 255) << 2;
    float lam = sc[5];
    float vr = v[row], wr = w[row];
    float4 p = ((const float4*)pu)[idx];
    float4 vc = *(const float4*)(v + c0);
    float4 wc = *(const float4*)(w + c0);
    float4 d;
    d.x = (float)NN * (fabsf(p.x) - vr * wc.x - wr * vc.x + lam * vr * vc.x);
    d.y = (float)NN * (fabsf(p.y) - vr * wc.y - wr * vc.y + lam * vr * vc.y);
    d.z = (float)NN * (fabsf(p.z) - vr * wc.z - wr * vc.z + lam * vr * vc.z);
    d.w = (float)NN * (fabsf(p.w) - vr * wc.w - wr * vc.w + lam * vr * vc.w);
    int dd = row - c0;
    if (dd == 0) d.x += EPS_SHIFT;
    else if (dd == 1) d.y += EPS_SHIFT;
    else if (dd == 2) d.z += EPS_SHIFT;
    else if (dd == 3) d.w += EPS_SHIFT;
    ((float4*)D)[idx] = d;
    float ss = d.x * d.x + d.y * d.y + d.z * d.z + d.w * d.w;
    ss = block_sum(ss);
    if (threadIdx.x == 0) atomicAdd(sc, ss);
}

// sc[0]=||D||_F^2, sc[5]=lam~  ->  sc[1]=1/c, sc[2]=sqrt(c), sc[4]=sqrt(N*lam~)
__global__ void finalize_kernel(float* sc) {
    float c = sqrtf(sc[0]);
    sc[1] = 1.f / c;
    sc[2] = sqrtf(c);
    sc[4] = sqrtf((float)NN * sc[5]);
}

// Y0 = D / c ; Z0 = I
__global__ __launch_bounds__(256) void init_kernel(const float* __restrict__ D,
                                                   const float* __restrict__ sc,
                                                   float* __restrict__ Y,
                                                   float* __restrict__ Z) {
    int idx = blockIdx.x * 256 + threadIdx.x;
    float s = sc[1];
    float4 v = ((const float4*)D)[idx];
    float4 y; y.x = v.x * s; y.y = v.y * s; y.z = v.z * s; y.w = v.w * s;
    ((float4*)Y)[idx] = y;
    int row = idx >> 8, cb = (idx & 255) << 2;
    float4 z;
    z.x = (row == cb + 0) ? 1.f : 0.f;
    z.y = (row == cb + 1) ? 1.f : 0.f;
    z.z = (row == cb + 2) ? 1.f : 0.f;
    z.w = (row == cb + 3) ? 1.f : 0.f;
    ((float4*)Z)[idx] = z;
}

// ---------- 128x128 tile SGEMM body, 8x8 micro, split-K atomic epilogue ----------
// optional W-transform on A or B loads: w = 1.5*[r==c] - 0.5*m  (i.e. (3I-M)/2)
__device__ __forceinline__ void stage_tiles(float* AsB, float* BsB,
                                            float4 a0, float4 a1, float4 b0, float4 b1,
                                            int am, int ak8, int bk, int bn8,
                                            int agr, int agc0, int bgr, int bgc0,
                                            int transA, int transB) {
    float av[8] = {a0.x, a0.y, a0.z, a0.w, a1.x, a1.y, a1.z, a1.w};
    if (transA) {
        #pragma unroll
        for (int i = 0; i < 8; ++i)
            av[i] = ((agr == agc0 + i) ? 1.5f : 0.f) - 0.5f * av[i];
    }
    #pragma unroll
    for (int i = 0; i < 8; ++i) AsB[(ak8 + i) * LDP + am] = av[i];
    if (transB) {
        float bv[8] = {b0.x, b0.y, b0.z, b0.w, b1.x, b1.y, b1.z, b1.w};
        #pragma unroll
        for (int i = 0; i < 8; ++i)
            bv[i] = ((bgr == bgc0 + i) ? 1.5f : 0.f) - 0.5f * bv[i];
        b0 = make_float4(bv[0], bv[1], bv[2], bv[3]);
        b1 = make_float4(bv[4], bv[5], bv[6], bv[7]);
    }
    *(float4*)&BsB[bk * LDP + bn8] = b0;
    *(float4*)&BsB[bk * LDP + bn8 + 4] = b1;
}

__device__ __forceinline__ void gemm_dev(const float* __restrict__ A,
                                         const float* __restrict__ B,
                                         float* __restrict__ C,
                                         int row0, int col0, int kbase, int nkt,
                                         int transA, int transB) {
    __shared__ float As[2][BK * LDP];
    __shared__ float Bs[2][BK * LDP];
    const int t = threadIdx.x;
    const int am = t >> 1, ak8 = (t & 1) << 3;     // A stage: row am, k ak8..+8
    const int bk = t >> 4, bn8 = (t & 15) << 3;    // B stage: k bk, col bn8..+8
    const int tx = t & 15, ty = t >> 4;            // micro coords

    const float* Ap = A + (size_t)(row0 + am) * NN + ak8;
    const float* Bp = B + (size_t)(kbase + bk) * NN + col0 + bn8;

    float acc[8][8];
    #pragma unroll
    for (int i = 0; i < 8; ++i)
        #pragma unroll
        for (int j = 0; j < 8; ++j) acc[i][j] = 0.f;

    {
        float4 a0 = *(const float4*)(Ap + kbase);
        float4 a1 = *(const float4*)(Ap + kbase + 4);
        float4 b0 = *(const float4*)(Bp);
        float4 b1 = *(const float4*)(Bp + 4);
        stage_tiles(As[0], Bs[0], a0, a1, b0, b1, am, ak8, bk, bn8,
                    row0 + am, kbase + ak8, kbase + bk, col0 + bn8, transA, transB);
    }
    __syncthreads();

    int buf = 0;
    for (int kt = 0; kt < nkt; ++kt) {
        float4 a0, a1, b0, b1;
        const bool more = (kt + 1 < nkt);
        if (more) {
            a0 = *(const float4*)(Ap + kbase + (kt + 1) * BK);
            a1 = *(const float4*)(Ap + kbase + (kt + 1) * BK + 4);
            b0 = *(const float4*)(Bp + (size_t)(kt + 1) * BK * NN);
            b1 = *(const float4*)(Bp + (size_t)(kt + 1) * BK * NN + 4);
        }
        #pragma unroll
        for (int kk = 0; kk < BK; ++kk) {
            float4 af0 = *(const float4*)&As[buf][kk * LDP + 4 * ty];
            float4 af1 = *(const float4*)&As[buf][kk * LDP + 4 * ty + 64];
            float4 bf0 = *(const float4*)&Bs[buf][kk * LDP + 4 * tx];
            float4 bf1 = *(const float4*)&Bs[buf][kk * LDP + 4 * tx + 64];
            float a_[8] = {af0.x, af0.y, af0.z, af0.w, af1.x, af1.y, af1.z, af1.w};
            float b_[8] = {bf0.x, bf0.y, bf0.z, bf0.w, bf1.x, bf1.y, bf1.z, bf1.w};
            #pragma unroll
            for (int i = 0; i < 8; ++i)
                #pragma unroll
                for (int j = 0; j < 8; ++j)
                    acc[i][j] = fmaf(a_[i], b_[j], acc[i][j]);
        }
        if (more)
            stage_tiles(As[buf ^ 1], Bs[buf ^ 1], a0, a1, b0, b1, am, ak8, bk, bn8,
                        row0 + am, kbase + (kt + 1) * BK + ak8,
                        kbase + (kt + 1) * BK + bk, col0 + bn8, transA, transB);
        __syncthreads();
        buf ^= 1;
    }

    #pragma unroll
    for (int i = 0; i < 8; ++i) {
        int r = row0 + 4 * ty + ((i < 4) ? i : 64 + (i - 4));
        float* Cr = C + (size_t)r * NN + col0;
        #pragma unroll
        for (int j = 0; j < 8; ++j) {
            int c = 4 * tx + ((j < 4) ? j : 64 + (j - 4));
            atomicAdd(Cr + c, acc[i][j]);
        }
    }
}

// single GEMM, split-K=4 (z), optional transforms: C += op(A)*op(B)
__global__ __launch_bounds__(256) void k_gemm4(const float* __restrict__ A,
                                               const float* __restrict__ B,
                                               float* __restrict__ C,
                                               int transA, int transB) {
    gemm_dev(A, B, C, blockIdx.y * TS, blockIdx.x * TS,
             blockIdx.z * (NN / 4), (NN / 4) / BK, transA, transB);
}

// dual stage-2: z>>1 selects gemm, z&1 selects K-split (K/2 each)
// gemm0: Yn += Y * W(M)   gemm1: Zn += W(M) * Z
__global__ __launch_bounds__(256) void k_stage2(const float* __restrict__ Y,
                                                const float* __restrict__ Z,
                                                const float* __restrict__ M,
                                                float* __restrict__ Yn,
                                                float* __restrict__ Zn) {
    int gem = blockIdx.z >> 1, sp = blockIdx.z & 1;
    int kbase = sp * (NN / 2), nkt = (NN / 2) / BK;
    if (gem == 0)
        gemm_dev(Y, M, Yn, blockIdx.y * TS, blockIdx.x * TS, kbase, nkt, 0, 1);
    else
        gemm_dev(M, Z, Zn, blockIdx.y * TS, blockIdx.x * TS, kbase, nkt, 1, 0);
}

// Zn = (3I - M)/2 elementwise (iter-0 shortcut, Z0 = I)
__global__ __launch_bounds__(256) void k_wwrite(const float* __restrict__ M,
                                                float* __restrict__ Zn) {
    int idx = blockIdx.x * 256 + threadIdx.x;
    int row = idx >> 8, c0 = (idx & 255) << 2;
    float4 m = ((const float4*)M)[idx];
    float4 o;
    o.x = -0.5f * m.x; o.y = -0.5f * m.y; o.z = -0.5f * m.z; o.w = -0.5f * m.w;
    int dd = row - c0;
    if (dd == 0) o.x += 1.5f;
    else if (dd == 1) o.y += 1.5f;
    else if (dd == 2) o.z += 1.5f;
    else if (dd == 3) o.w += 1.5f;
    ((float4*)Zn)[idx] = o;
}

// P = sqrt(c)*(Y+Y^T)/2 + sqrt(N*lam)*v v^T
__global__ __launch_bounds__(256) void sym_kernel(const float* __restrict__ Y,
                                                  const float* __restrict__ sc,
                                                  const float* __restrict__ v,
                                                  float* __restrict__ P) {
    __shared__ float tile[32][33];
    int i0 = blockIdx.y * 32, j0 = blockIdx.x * 32;
    int tx = threadIdx.x & 31, ty = threadIdx.x >> 5;  // block 256 = (32,8)
    #pragma unroll
    for (int r = 0; r < 4; ++r)
        tile[ty + 8 * r][tx] = Y[(size_t)(j0 + ty + 8 * r) * NN + i0 + tx];
    __syncthreads();
    float s = 0.5f * sc[2], s1 = sc[4];
    float vj = v[j0 + tx];
    #pragma unroll
    for (int r = 0; r < 4; ++r) {
        int i = i0 + ty + 8 * r;
        P[(size_t)i * NN + j0 + tx] =
            s * (Y[(size_t)i * NN + j0 + tx] + tile[tx][ty + 8 * r]) + s1 * v[i] * vj;
    }
}

// out0[b][n][m] = d_b[n]*d_b[m] + |P_u[n,m]| + 0.01*Q_k[n,m]^2 ; d_b = x[0,:]-x[b,:]
__global__ __launch_bounds__(256) void out0_kernel(const float* __restrict__ x,
                                                   const float* __restrict__ pu,
                                                   const float* __restrict__ qk,
                                                   float* __restrict__ out) {
    int i = blockIdx.x * blockDim.x + threadIdx.x;  // over BB*NN*NN/4
    int rem = i & (NN * NN / 4 - 1);
    int b = i >> 18;
    int n = rem >> 8;
    int m4 = (rem & 255) << 2;
    float dn = x[n] - x[b * NN + n];
    float4 x0v = *(const float4*)(x + m4);
    float4 xbv = *(const float4*)(x + b * NN + m4);
    float4 pv = ((const float4*)pu)[rem];
    float4 qv = ((const float4*)qk)[rem];
    float4 o;
    o.x = dn * (x0v.x - xbv.x) + fabsf(pv.x) + 0.01f * qv.x * qv.x;
    o.y = dn * (x0v.y - xbv.y) + fabsf(pv.y) + 0.01f * qv.y * qv.y;
    o.z = dn * (x0v.z - xbv.z) + fabsf(pv.z) + 0.01f * qv.z * qv.z;
    o.w = dn * (x0v.w - xbv.w) + fabsf(pv.w) + 0.01f * qv.w * qv.w;
    ((float4*)out)[i] = o;
}

// out1[0][b][j][i] = x[b][i] + (j<N ? +P[j][i] : -P[j-N][i])
__global__ __launch_bounds__(256) void out1_kernel(const float* __restrict__ x,
                                                   const float* __restrict__ P,
                                                   float* __restrict__ out) {
    int i = blockIdx.x * blockDim.x + threadIdx.x;  // over BB*2N*NN/4
    int bj = i >> 8;
    int i4 = (i & 255) << 2;
    int b = bj >> 11;
    int j = bj & 2047;
    float s = (j < NN) ? 1.f : -1.f;
    int row = (j < NN) ? j : j - NN;
    float4 pv = *(const float4*)(P + (size_t)row * NN + i4);
    float4 xv = *(const float4*)(x + b * NN + i4);
    float4 o;
    o.x = xv.x + s * pv.x; o.y = xv.y + s * pv.y;
    o.z = xv.z + s * pv.z; o.w = xv.w + s * pv.w;
    ((float4*)out)[i] = o;
}

extern "C" void kernel_launch(void* const* d_in, const int* in_sizes, int n_in,
                              void* d_out, int out_size, void* d_ws, size_t ws_size,
                              hipStream_t stream) {
    const float* x  = (const float*)d_in[0];
    const float* pu = (const float*)d_in[1];
    const float* qk = (const float*)d_in[2];
    float* out = (float*)d_out;
    char* ws = (char*)d_ws;
    // layout: YA ZA M YB ZB D P  (4MB each), then vectors + scalars
    float* YA = (float*)(ws + (size_t)0 * 4 * MB);
    float* ZA = (float*)(ws + (size_t)1 * 4 * MB);
    float* M  = (float*)(ws + (size_t)2 * 4 * MB);
    float* YB = (float*)(ws + (size_t)3 * 4 * MB);
    float* ZB = (float*)(ws + (size_t)4 * 4 * MB);
    float* D  = (float*)(ws + (size_t)5 * 4 * MB);
    float* P  = (float*)(ws + (size_t)6 * 4 * MB);
    float* vv = (float*)(ws + (size_t)28 * MB);
    float* vw = (float*)(ws + (size_t)28 * MB + 4096);
    float* vt = (float*)(ws + (size_t)28 * MB + 8192);
    float* sc = (float*)(ws + (size_t)28 * MB + 12288);

    // ---- deflation: top eigpair of |P_u| via 3 matvecs ----
    hipMemsetAsync(sc, 0, 64, stream);
    matvec_abs<<<NN, 256, 0, stream>>>(pu, vv, vt, 1);
    norm_vec<<<1, 256, 0, stream>>>(vt, vv);
    matvec_abs<<<NN, 256, 0, stream>>>(pu, vv, vt, 0);
    norm_vec<<<1, 256, 0, stream>>>(vt, vv);
    matvec_abs<<<NN, 256, 0, stream>>>(pu, vv, vw, 0);
    dot_vec<<<1, 256, 0, stream>>>(vv, vw, sc + 5);
    deflate_kernel<<<NN * NN / 4 / 256, 256, 0, stream>>>(pu, vv, vw, sc, D);
    finalize_kernel<<<1, 1, 0, stream>>>(sc);
    init_kernel<<<NN * NN / 4 / 256, 256, 0, stream>>>(D, sc, YA, ZA);

    // ---- coupled Newton-Schulz ----
    float *Y = YA, *Z = ZA, *Yn = YB, *Zn = ZB;
    for (int it = 0; it < NS_ITERS; ++it) {
        // zero {M, Ynew, Znew}: contiguous 12MB either side of M
        char* mz = (it & 1) ? ws : ws + (size_t)8 * MB;
        hipMemsetAsync(mz, 0, (size_t)12 * MB, stream);
        if (it == 0) {
            // M == Y0 (Z0 = I); Yn = Y0*W(Y0); Zn = W(Y0) elementwise
            k_stage2<<<dim3(8, 8, 2), 256, 0, stream>>>(Y, Z, Y, Yn, Zn);
            k_wwrite<<<NN * NN / 4 / 256, 256, 0, stream>>>(Y, Zn);
        } else {
            k_gemm4<<<dim3(8, 8, 4), 256, 0, stream>>>(Z, Y, M, 0, 0);  // M = Z*Y
            if (it + 1 == NS_ITERS) {
                k_gemm4<<<dim3(8, 8, 4), 256, 0, stream>>>(Y, M, Yn, 0, 1);  // Yn = Y*W
            } else {
                k_stage2<<<dim3(8, 8, 4), 256, 0, stream>>>(Y, Z, M, Yn, Zn);
            }
        }
        float* t1 = Y; Y = Yn; Yn = t1;
        float* t2 = Z; Z = Zn; Zn = t2;
    }

    sym_kernel<<<dim3(32, 32, 1), 256, 0, stream>>>(Y, sc, vv, P);
    out0_kernel<<<(BB * NN * NN / 4) / 256, 256, 0, stream>>>(x, pu, qk, out);
    out1_kernel<<<(BB * 2 * NN * NN / 4) / 256, 256, 0, stream>>>(
        x, P, out + (size_t)BB * NN * NN);
}

// Round 5
// 969.427 us; speedup vs baseline: 3.6902x; 3.6902x over previous
//
#include <hip/hip_runtime.h>
#include <math.h>

#define NN 1024
#define BB 8
#define NS_ITERS 10
#define EPS_SHIFT 4.0f
#define MB (1u<<20)

typedef __attribute__((ext_vector_type(8))) short short8;
typedef __attribute__((ext_vector_type(4))) float floatx4;

__device__ __forceinline__ ushort f2bf(float f) {
    union { float f; uint32_t u; } v; v.f = f;
    uint32_t u = v.u;
    uint32_t r = (u + 0x7fffu + ((u >> 16) & 1u)) >> 16;
    return (ushort)r;
}
__device__ __forceinline__ float bf2f(ushort h) {
    union { uint32_t u; float f; } v; v.u = ((uint32_t)h) << 16;
    return v.f;
}

// ---------- block reduction helper (result valid on thread 0) ----------
__device__ __forceinline__ float block_sum(float v) {
    #pragma unroll
    for (int off = 32; off > 0; off >>= 1) v += __shfl_down(v, off, 64);
    __shared__ float red[4];
    int lane = threadIdx.x & 63, wid = threadIdx.x >> 6;
    if (lane == 0) red[wid] = v;
    __syncthreads();
    float t = 0.f;
    if (threadIdx.x == 0) t = red[0] + red[1] + red[2] + red[3];
    return t;
}

// ---------- power iteration pieces: y[row] = sum_j |pu[row][j]| * x[j] ----------
__global__ __launch_bounds__(256) void matvec_abs(const float* __restrict__ pu,
                                                  const float* __restrict__ x,
                                                  float* __restrict__ y,
                                                  int use_ones) {
    int row = blockIdx.x;
    const float4* pr = (const float4*)(pu + (size_t)row * NN);
    float4 p = pr[threadIdx.x];
    float s;
    if (use_ones) {
        s = fabsf(p.x) + fabsf(p.y) + fabsf(p.z) + fabsf(p.w);
    } else {
        float4 xx = ((const float4*)x)[threadIdx.x];
        s = fabsf(p.x) * xx.x + fabsf(p.y) * xx.y + fabsf(p.z) * xx.z + fabsf(p.w) * xx.w;
    }
    s = block_sum(s);
    if (threadIdx.x == 0) y[row] = s;
}

__global__ void norm_vec(const float* __restrict__ y, float* __restrict__ v) {
    float ss = 0.f;
    for (int i = threadIdx.x; i < NN; i += 256) { float t = y[i]; ss += t * t; }
    #pragma unroll
    for (int off = 32; off > 0; off >>= 1) ss += __shfl_down(ss, off, 64);
    __shared__ float red[4];
    __shared__ float s_inv;
    int lane = threadIdx.x & 63, wid = threadIdx.x >> 6;
    if (lane == 0) red[wid] = ss;
    __syncthreads();
    if (threadIdx.x == 0) s_inv = rsqrtf(red[0] + red[1] + red[2] + red[3]);
    __syncthreads();
    float inv = s_inv;
    for (int i = threadIdx.x; i < NN; i += 256) v[i] = y[i] * inv;
}

__global__ void dot_vec(const float* __restrict__ a, const float* __restrict__ b,
                        float* __restrict__ out) {
    float s = 0.f;
    for (int i = threadIdx.x; i < NN; i += 256) s += a[i] * b[i];
    s = block_sum(s);
    if (threadIdx.x == 0) out[0] = s;
}

// ---------- deflation: D = N*(|pu| - v w^T - w v^T + lam v v^T) + eps*I ----------
__global__ __launch_bounds__(256) void deflate_kernel(const float* __restrict__ pu,
                                                      const float* __restrict__ v,
                                                      const float* __restrict__ w,
                                                      float* __restrict__ sc,
                                                      float* __restrict__ D) {
    int idx = blockIdx.x * 256 + threadIdx.x;   // over NN*NN/4
    int row = idx >> 8;
    int c0 = (idx & 255) << 2;
    float lam = sc[5];
    float vr = v[row], wr = w[row];
    float4 p = ((const float4*)pu)[idx];
    float4 vc = *(const float4*)(v + c0);
    float4 wc = *(const float4*)(w + c0);
    float4 d;
    d.x = (float)NN * (fabsf(p.x) - vr * wc.x - wr * vc.x + lam * vr * vc.x);
    d.y = (float)NN * (fabsf(p.y) - vr * wc.y - wr * vc.y + lam * vr * vc.y);
    d.z = (float)NN * (fabsf(p.z) - vr * wc.z - wr * vc.z + lam * vr * vc.z);
    d.w = (float)NN * (fabsf(p.w) - vr * wc.w - wr * vc.w + lam * vr * vc.w);
    int dd = row - c0;
    if (dd == 0) d.x += EPS_SHIFT;
    else if (dd == 1) d.y += EPS_SHIFT;
    else if (dd == 2) d.z += EPS_SHIFT;
    else if (dd == 3) d.w += EPS_SHIFT;
    ((float4*)D)[idx] = d;
    float ss = d.x * d.x + d.y * d.y + d.z * d.z + d.w * d.w;
    ss = block_sum(ss);
    if (threadIdx.x == 0) atomicAdd(sc, ss);
}

// sc[0]=||D||_F^2, sc[5]=lam~  ->  sc[1]=1/c, sc[2]=sqrt(c), sc[4]=sqrt(N*lam~)
__global__ void finalize_kernel(float* sc) {
    float c = sqrtf(sc[0]);
    sc[1] = 1.f / c;
    sc[2] = sqrtf(c);
    sc[4] = sqrtf((float)NN * sc[5]);
}

// ---------- MFMA GEMM: 64x64 tile, 128 threads (2 waves), split-bf16 fp32 ----------
// C[row0..+64)[col0..+64) over fp32-k in [kb,kb+kc): Ahi*Bhi + Alo*Bhi + Ahi*Blo
// B is symmetric: stage B by output-col rows (gemm_bt pattern, no transpose).
__device__ __forceinline__ void mm_dev(const ushort* __restrict__ Ah,
                                       const ushort* __restrict__ Al,
                                       const ushort* __restrict__ Bh,
                                       const ushort* __restrict__ Bl,
                                       int row0, int col0, int kb, int kc,
                                       float* __restrict__ Cf,
                                       ushort* __restrict__ Chi,
                                       ushort* __restrict__ Clo) {
    __shared__ __align__(16) ushort As[64 * 32];
    __shared__ __align__(16) ushort Bs[64 * 32];
    const int t = threadIdx.x;          // 0..127
    const int w = t >> 6, l = t & 63;
    const int fm = l & 15, fq = l >> 4;
    const int srow = t >> 2;            // staging row (second issue adds +32)
    const int scol = (t & 3) << 3;      // staging col (8 bf16 = 16B)

    floatx4 acc[4][2];
    #pragma unroll
    for (int mi = 0; mi < 4; ++mi) {
        acc[mi][0] = (floatx4)0.f;
        acc[mi][1] = (floatx4)0.f;
    }

    #pragma unroll 1
    for (int p = 0; p < 3; ++p) {
        const ushort* Aa = (p == 1) ? Al : Ah;
        const ushort* Bb = (p == 2) ? Bl : Bh;
        const ushort* Ap0 = Aa + (size_t)(row0 + srow) * NN + kb + scol;
        const ushort* Ap1 = Ap0 + (size_t)32 * NN;
        const ushort* Bp0 = Bb + (size_t)(col0 + srow) * NN + kb + scol;
        const ushort* Bp1 = Bp0 + (size_t)32 * NN;
        #pragma unroll 1
        for (int kt = 0; kt < kc; kt += 32) {
            short8 a0 = *(const short8*)(Ap0 + kt);
            short8 a1 = *(const short8*)(Ap1 + kt);
            short8 b0 = *(const short8*)(Bp0 + kt);
            short8 b1 = *(const short8*)(Bp1 + kt);
            __syncthreads();   // previous iteration's LDS readers done
            *(short8*)&As[t << 3] = a0;
            *(short8*)&As[(t << 3) + 1024] = a1;
            *(short8*)&Bs[t << 3] = b0;
            *(short8*)&Bs[(t << 3) + 1024] = b1;
            __syncthreads();   // staging visible
            short8 bf0 = *(const short8*)&Bs[((w << 5) + fm) * 32 + (fq << 3)];
            short8 bf1 = *(const short8*)&Bs[((w << 5) + 16 + fm) * 32 + (fq << 3)];
            #pragma unroll
            for (int mi = 0; mi < 4; ++mi) {
                short8 af = *(const short8*)&As[((mi << 4) + fm) * 32 + (fq << 3)];
                acc[mi][0] = __builtin_amdgcn_mfma_f32_16x16x32_bf16(af, bf0, acc[mi][0], 0, 0, 0);
                acc[mi][1] = __builtin_amdgcn_mfma_f32_16x16x32_bf16(af, bf1, acc[mi][1], 0, 0, 0);
            }
        }
    }

    // epilogue: C/D layout col=lane&15, row=(lane>>4)*4+reg (m89-verified)
    #pragma unroll
    for (int mi = 0; mi < 4; ++mi) {
        #pragma unroll
        for (int r = 0; r < 4; ++r) {
            int row = row0 + (mi << 4) + (fq << 2) + r;
            #pragma unroll
            for (int ni = 0; ni < 2; ++ni) {
                int col = col0 + (w << 5) + (ni << 4) + fm;
                float v = acc[mi][ni][r];
                size_t idx = (size_t)row * NN + col;
                if (Cf) {
                    Cf[idx] = v;
                } else {
                    ushort h = f2bf(v);
                    Chi[idx] = h;
                    Clo[idx] = f2bf(v - bf2f(h));
                }
            }
        }
    }
}

// stage-1: Mp[z] = partial (Z*Y) over half the K range (fp32 partials, no atomics)
__global__ __launch_bounds__(128) void k_stage1(const ushort* __restrict__ Zh,
                                                const ushort* __restrict__ Zl,
                                                const ushort* __restrict__ Yh,
                                                const ushort* __restrict__ Yl,
                                                float* __restrict__ Mp) {
    int s = blockIdx.z;
    mm_dev(Zh, Zl, Yh, Yl, blockIdx.y * 64, blockIdx.x * 64,
           s * (NN / 2), NN / 2, Mp + (size_t)s * NN * NN, nullptr, nullptr);
}

// stage-2: z=0: Yn = Y*W ; z=1: Zn = W*Z  (epilogue writes bf16 hi/lo directly)
__global__ __launch_bounds__(128) void k_stage2(const ushort* __restrict__ Yh,
                                                const ushort* __restrict__ Yl,
                                                const ushort* __restrict__ Wh,
                                                const ushort* __restrict__ Wl,
                                                const ushort* __restrict__ Zh,
                                                const ushort* __restrict__ Zl,
                                                ushort* __restrict__ Ynh,
                                                ushort* __restrict__ Ynl,
                                                ushort* __restrict__ Znh,
                                                ushort* __restrict__ Znl) {
    if (blockIdx.z == 0)
        mm_dev(Yh, Yl, Wh, Wl, blockIdx.y * 64, blockIdx.x * 64, 0, NN,
               nullptr, Ynh, Ynl);
    else
        mm_dev(Wh, Wl, Zh, Zl, blockIdx.y * 64, blockIdx.x * 64, 0, NN,
               nullptr, Znh, Znl);
}

// final: Yf = Y*W in fp32
__global__ __launch_bounds__(128) void k_final(const ushort* __restrict__ Yh,
                                               const ushort* __restrict__ Yl,
                                               const ushort* __restrict__ Wh,
                                               const ushort* __restrict__ Wl,
                                               float* __restrict__ Yf) {
    mm_dev(Yh, Yl, Wh, Wl, blockIdx.y * 64, blockIdx.x * 64, 0, NN,
           Yf, nullptr, nullptr);
}

// W = 1.5I - 0.25*(Mp0+Mp1+Mp0^T+Mp1^T) -> bf16 hi/lo  (symmetrized M)
__global__ __launch_bounds__(256) void k_wsplit(const float* __restrict__ Mp,
                                                ushort* __restrict__ Wh,
                                                ushort* __restrict__ Wl) {
    int i = blockIdx.x * 256 + threadIdx.x;     // float4 index over NN*NN/4
    int row = i >> 8, c0 = (i & 255) << 2;
    float4 m0 = ((const float4*)Mp)[i];
    float4 m1 = ((const float4*)Mp)[i + NN * NN / 4];
    float mr[4] = {m0.x + m1.x, m0.y + m1.y, m0.z + m1.z, m0.w + m1.w};
    float wv[4];
    #pragma unroll
    for (int j = 0; j < 4; ++j) {
        float mt = Mp[(size_t)(c0 + j) * NN + row] +
                   Mp[(size_t)(c0 + j) * NN + row + (size_t)NN * NN];
        wv[j] = -0.25f * (mr[j] + mt);
    }
    int dd = row - c0;
    if (dd >= 0 && dd < 4) wv[dd] += 1.5f;
    ushort4 hv, lv;
    ushort* hp = (ushort*)&hv; ushort* lp = (ushort*)&lv;
    #pragma unroll
    for (int j = 0; j < 4; ++j) {
        ushort h = f2bf(wv[j]); hp[j] = h; lp[j] = f2bf(wv[j] - bf2f(h));
    }
    *(ushort4*)&Wh[(size_t)i << 2] = hv;
    *(ushort4*)&Wl[(size_t)i << 2] = lv;
}

// iter0: Y0 = D/c -> split ; W0 = 1.5I - 0.5*Y0 -> split
__global__ __launch_bounds__(256) void k_wsplit0(const float* __restrict__ D,
                                                 const float* __restrict__ sc,
                                                 ushort* __restrict__ Yh,
                                                 ushort* __restrict__ Yl,
                                                 ushort* __restrict__ Wh,
                                                 ushort* __restrict__ Wl) {
    int i = blockIdx.x * 256 + threadIdx.x;
    int row = i >> 8, c0 = (i & 255) << 2;
    float invc = sc[1];
    float4 d = ((const float4*)D)[i];
    float yv[4] = {d.x * invc, d.y * invc, d.z * invc, d.w * invc};
    ushort4 yh, yl, wh, wl;
    ushort* yhp = (ushort*)&yh; ushort* ylp = (ushort*)&yl;
    ushort* whp = (ushort*)&wh; ushort* wlp = (ushort*)&wl;
    int dd = row - c0;
    #pragma unroll
    for (int j = 0; j < 4; ++j) {
        float y = yv[j];
        ushort h = f2bf(y); yhp[j] = h; ylp[j] = f2bf(y - bf2f(h));
        float wv = ((dd == j) ? 1.5f : 0.f) - 0.5f * y;
        ushort h2 = f2bf(wv); whp[j] = h2; wlp[j] = f2bf(wv - bf2f(h2));
    }
    *(ushort4*)&Yh[(size_t)i << 2] = yh;
    *(ushort4*)&Yl[(size_t)i << 2] = yl;
    *(ushort4*)&Wh[(size_t)i << 2] = wh;
    *(ushort4*)&Wl[(size_t)i << 2] = wl;
}

// out0[b][n][m] = d_b[n]*d_b[m] + |P_u[n,m]| + 0.01*Q_k[n,m]^2 ; d_b = x[0,:]-x[b,:]
__global__ __launch_bounds__(256) void out0_kernel(const float* __restrict__ x,
                                                   const float* __restrict__ pu,
                                                   const float* __restrict__ qk,
                                                   float* __restrict__ out) {
    int i = blockIdx.x * blockDim.x + threadIdx.x;  // over BB*NN*NN/4
    int rem = i & (NN * NN / 4 - 1);
    int b = i >> 18;
    int n = rem >> 8;
    int m4 = (rem & 255) << 2;
    float dn = x[n] - x[b * NN + n];
    float4 x0v = *(const float4*)(x + m4);
    float4 xbv = *(const float4*)(x + b * NN + m4);
    float4 pv = ((const float4*)pu)[rem];
    float4 qv = ((const float4*)qk)[rem];
    float4 o;
    o.x = dn * (x0v.x - xbv.x) + fabsf(pv.x) + 0.01f * qv.x * qv.x;
    o.y = dn * (x0v.y - xbv.y) + fabsf(pv.y) + 0.01f * qv.y * qv.y;
    o.z = dn * (x0v.z - xbv.z) + fabsf(pv.z) + 0.01f * qv.z * qv.z;
    o.w = dn * (x0v.w - xbv.w) + fabsf(pv.w) + 0.01f * qv.w * qv.w;
    ((float4*)out)[i] = o;
}

// fused sym + out1: p[j][i] = 0.5*sqrt(c)*(Yf[j][i]+Yf[i][j]) + sqrt(N*lam)*v[j]*v[i]
// out1[0][b][j][i] = x[b][i] + p ; out1[0][b][N+j][i] = x[b][i] - p
__global__ __launch_bounds__(256) void k_out1(const float* __restrict__ x,
                                              const float* __restrict__ Yf,
                                              const float* __restrict__ sc,
                                              const float* __restrict__ v,
                                              float* __restrict__ out1) {
    int i = blockIdx.x * 256 + threadIdx.x;     // over NN*NN/4
    int j = i >> 8, i0 = (i & 255) << 2;
    float s = 0.5f * sc[2], s1v = sc[4] * v[j];
    float4 yr = *(const float4*)(Yf + (size_t)j * NN + i0);
    float yc0 = Yf[(size_t)(i0 + 0) * NN + j];
    float yc1 = Yf[(size_t)(i0 + 1) * NN + j];
    float yc2 = Yf[(size_t)(i0 + 2) * NN + j];
    float yc3 = Yf[(size_t)(i0 + 3) * NN + j];
    float4 vc = *(const float4*)(v + i0);
    float4 p;
    p.x = s * (yr.x + yc0) + s1v * vc.x;
    p.y = s * (yr.y + yc1) + s1v * vc.y;
    p.z = s * (yr.z + yc2) + s1v * vc.z;
    p.w = s * (yr.w + yc3) + s1v * vc.w;
    #pragma unroll
    for (int b = 0; b < BB; ++b) {
        float4 xv = *(const float4*)(x + b * NN + i0);
        float4 a, m;
        a.x = xv.x + p.x; a.y = xv.y + p.y; a.z = xv.z + p.z; a.w = xv.w + p.w;
        m.x = xv.x - p.x; m.y = xv.y - p.y; m.z = xv.z - p.z; m.w = xv.w - p.w;
        float* base = out1 + (size_t)b * 2 * NN * NN;
        *(float4*)(base + (size_t)j * NN + i0) = a;
        *(float4*)(base + (size_t)(NN + j) * NN + i0) = m;
    }
}

extern "C" void kernel_launch(void* const* d_in, const int* in_sizes, int n_in,
                              void* d_out, int out_size, void* d_ws, size_t ws_size,
                              hipStream_t stream) {
    const float* x  = (const float*)d_in[0];
    const float* pu = (const float*)d_in[1];
    const float* qk = (const float*)d_in[2];
    float* out = (float*)d_out;
    char* ws = (char*)d_ws;

    // layout: [0,8MB) fp32 Mp0/Mp1 (Mp0 doubles as D before iter1 and Yf after
    // last wsplit); [8MB,28MB) five bf16 hi/lo pairs (4MB each); vectors after.
    float* Mp = (float*)ws;
    float* D  = Mp;
    float* Yf = Mp;
    ushort* hi[5]; ushort* lo[5];
    for (int k = 0; k < 5; ++k) {
        hi[k] = (ushort*)(ws + (size_t)8 * MB + (size_t)k * 4 * MB);
        lo[k] = (ushort*)(ws + (size_t)8 * MB + (size_t)k * 4 * MB + 2 * MB);
    }
    float* vv = (float*)(ws + (size_t)28 * MB);
    float* vw = (float*)(ws + (size_t)28 * MB + 4096);
    float* vt = (float*)(ws + (size_t)28 * MB + 8192);
    float* sc = (float*)(ws + (size_t)28 * MB + 12288);

    // ---- deflation: top eigpair of |P_u| via 3 matvecs ----
    hipMemsetAsync(sc, 0, 64, stream);
    matvec_abs<<<NN, 256, 0, stream>>>(pu, vv, vt, 1);
    norm_vec<<<1, 256, 0, stream>>>(vt, vv);
    matvec_abs<<<NN, 256, 0, stream>>>(pu, vv, vt, 0);
    norm_vec<<<1, 256, 0, stream>>>(vt, vv);
    matvec_abs<<<NN, 256, 0, stream>>>(pu, vv, vw, 0);
    dot_vec<<<1, 256, 0, stream>>>(vv, vw, sc + 5);
    deflate_kernel<<<NN * NN / 4 / 256, 256, 0, stream>>>(pu, vv, vw, sc, D);
    finalize_kernel<<<1, 1, 0, stream>>>(sc);

    // ---- iter 0: Y0,W0 from D; Y1 = Y0*W0 ; Z1 = W0 (pointer swap) ----
    k_wsplit0<<<NN * NN / 4 / 256, 256, 0, stream>>>(D, sc, hi[0], lo[0], hi[1], lo[1]);
    k_stage2<<<dim3(16, 16, 1), 128, 0, stream>>>(hi[0], lo[0], hi[1], lo[1],
                                                  hi[0], lo[0],   // Z unused (z=0 only)
                                                  hi[2], lo[2], hi[3], lo[3]);
    int Y = 2, Z = 1, f0 = 0, f1 = 3, f2 = 4;

    // ---- iters 1..NS_ITERS-1 ----
    for (int it = 1; it < NS_ITERS; ++it) {
        int W = f0;
        k_stage1<<<dim3(16, 16, 2), 128, 0, stream>>>(hi[Z], lo[Z], hi[Y], lo[Y], Mp);
        k_wsplit<<<NN * NN / 4 / 256, 256, 0, stream>>>(Mp, hi[W], lo[W]);
        if (it + 1 < NS_ITERS) {
            int Yn = f1, Zn = f2;
            k_stage2<<<dim3(16, 16, 2), 128, 0, stream>>>(
                hi[Y], lo[Y], hi[W], lo[W], hi[Z], lo[Z],
                hi[Yn], lo[Yn], hi[Zn], lo[Zn]);
            f0 = Y; f1 = Z; f2 = W;
            Y = Yn; Z = Zn;
        } else {
            k_final<<<dim3(16, 16, 1), 128, 0, stream>>>(hi[Y], lo[Y], hi[W], lo[W], Yf);
        }
    }

    // ---- outputs ----
    out0_kernel<<<(BB * NN * NN / 4) / 256, 256, 0, stream>>>(x, pu, qk, out);
    k_out1<<<NN * NN / 4 / 256, 256, 0, stream>>>(x, Yf, sc, vv,
                                                  out + (size_t)BB * NN * NN);
}